// Round 18
// baseline (282.695 us; speedup 1.0000x reference)
//
#include <hip/hip_runtime.h>
#include <math.h>

typedef unsigned short u16;
typedef unsigned int u32;
typedef unsigned long long u64;
typedef __attribute__((ext_vector_type(8))) short short8;
typedef __attribute__((ext_vector_type(16))) float f32x16;

#define NVEC   32768
#define DIMV   64
#define KC     8192
#define NKCH   8
#define CHK    1024
#define HW     1024
#define BPLANE 65536
#define NSTEP  (CHK / 32)   // 32 staged steps of 32 codes

// output offsets (floats)
#define OFF_Q    0
#define OFF_IDX  2097152
#define OFF_LOSS 2129920
#define OFF_PPL  2129921
#define OFF_ACT  2129922
#define OFF_NCB  2129923
#define OFF_NCS  2654211
#define OFF_NEA  2662403

// workspace offsets (floats)
#define WS_COUNTS 0        // 8192
#define WS_SCAL   8192     // 8
#define WS_C2     8200     // 8192
#define WS_MINP   16400    // 65536 (32768 u64, 8B-aligned)
#define WS_OFFS   81936    // 8192 int
#define WS_PERM   90128    // 32768 int
#define WS_CBF    122896   // 786432 floats = 1572864 u16 (fragment-major 3-split, 32-code tiles)

__device__ __forceinline__ u16 f2bf(float x) {
    u32 u = __float_as_uint(x);
    u += 0x7fffu + ((u >> 16) & 1u);   // RNE
    return (u16)(u >> 16);
}
__device__ __forceinline__ float bf2f(u16 h) {
    return __uint_as_float(((u32)h) << 16);
}
__device__ __forceinline__ u32 fmono(float f) {   // monotone float->u32
    u32 b = __float_as_uint(f);
    return (b & 0x80000000u) ? ~b : (b | 0x80000000u);
}

// ---------------- codebook bf16 3-split (32-code-tile fragment-major) + c2 + ws init ----------------
// cbf layout per 32-code tile ti (6144 u16 = 12KB): term t=0..2 {h,m,l} x 4KB;
// within a term, kstep ks=0..3 x 1KB; within that, lane l = (code&31) + 32*((d>>3)&1)
// holds 8 u16 at l*8 (+ e = d&7), i.e. k = ks*16 + (l>>5)*8 + e.
// 6-term is REQUIRED: 3-term (r11) flipped indices (absmax 1952) — margin floor < 4e-4.
__global__ __launch_bounds__(256) void cbsplit_kernel(const float* __restrict__ cb,
                                                      u16* __restrict__ cbf,
                                                      float* __restrict__ c2,
                                                      float* __restrict__ counts,
                                                      float* __restrict__ scal,
                                                      u64* __restrict__ minp) {
    const int t = threadIdx.x;
    const int gid = blockIdx.x * 256 + t;
    if (gid < 8192) counts[gid] = 0.f;
    if (gid < 8) scal[gid] = 0.f;
    if (gid < NVEC) minp[gid] = ~0ull;

    const int k = blockIdx.x * 4 + (t >> 6);
    const int d = t & 63;
    const int idx = k * DIMV + d;
    float x = cb[idx];
    u16 hb = f2bf(x);  float fh = bf2f(hb);
    float r1 = x - fh; u16 mb = f2bf(r1); float fm = bf2f(mb);
    float r2 = r1 - fm; u16 lb = f2bf(r2);
    const int ti = k >> 5, c5 = k & 31;
    const int ks = d >> 4;
    const int g = (d >> 3) & 1;
    const int e = d & 7;
    u16* base = cbf + (size_t)ti * 6144 + ks * 512 + (c5 + 32 * g) * 8 + e;
    base[0 * 2048] = hb;
    base[1 * 2048] = mb;
    base[2 * 2048] = lb;
    float s = x * x;
    for (int off = 32; off > 0; off >>= 1) s += __shfl_down(s, off, 64);
    if (d == 0) c2[k] = s;
}

// stage 32 codes (12KB, linear region of cbf) into LDS buffer B (async, 3x16B/thread)
#define STAGE(B, ST)                                                                \
    _Pragma("unroll")                                                               \
    for (int j = 0; j < 3; ++j) {                                                   \
        const u16* gs = pcbf + (size_t)(ST) * 6144 + j * 2048 + tl * 8;             \
        u16* ld = &ldsb[B][j * 2048 + wv * 512];                                    \
        __builtin_amdgcn_global_load_lds(                                           \
            (const __attribute__((address_space(1))) void*)gs,                      \
            (__attribute__((address_space(3))) void*)ld, 16, 0, 0);                 \
    }

// ---------------- MFMA nearest-neighbor search (32x32x16, 2 independent acc chains) ----------------
// r17 lesson: ONE f32x16 acc chain = 24 serially-dependent MFMAs -> latency-bound
// (util 54%, 177us). Fix: acc0 covers ks=0,1; acc1 covers ks=2,3 (12-deep chains,
// compiler interleaves) -> pipe stays fed. Sum acc0+acc1 before argmin.
// C/D row = (reg&3)+8*(reg>>2)+4*(lane>>5) (m74/m101, verified by r17 passing).
__global__ __launch_bounds__(256, 3) void nn_kernel(const float* __restrict__ z,
                                                    const u16* __restrict__ cbf,
                                                    const float* __restrict__ c2,
                                                    u64* __restrict__ minp) {
    __shared__ __align__(16) u16 ldsb[2][6144];   // 24KB: 2 buf x 32 codes x 3 terms x 4 ksteps
    const int tl = threadIdx.x;
    const int l  = tl & 63;
    const int wv = tl >> 6;
    const int vg = blockIdx.x;      // 0..255 vector groups (128 vecs)
    const int kc = blockIdx.y;      // 0..7 code chunks (1024 codes)
    const int m0 = vg * 128 + wv * 32;
    const int hi = l >> 5;
    const int vec = m0 + (l & 31);

    // z fragments: 3 splits x 4 ksteps, lane = vector col, k = ks*16 + hi*8 + e
    short8 Z[3][4];
    {
        const float* zp = z + (size_t)(vec >> 10) * BPLANE + (vec & 1023);
#pragma unroll
        for (int ks = 0; ks < 4; ++ks) {
            short8 zh, zm, zl;
#pragma unroll
            for (int e = 0; e < 8; ++e) {
                const int k = ks * 16 + hi * 8 + e;
                float x = zp[k * HW];
                u16 hb = f2bf(x);   float fh = bf2f(hb);
                float r1 = x - fh;  u16 mb = f2bf(r1); float fm = bf2f(mb);
                float r2 = r1 - fm; u16 lb = f2bf(r2);
                zh[e] = (short)hb; zm[e] = (short)mb; zl[e] = (short)lb;
            }
            Z[0][ks] = zh; Z[1][ks] = zm; Z[2][ks] = zl;
        }
    }

    float bestv = -3.4e38f;
    int   besti = 0;

    const int code_base = kc * CHK;
    const float* pc2 = c2 + code_base;
    const u16* pcbf = cbf + (size_t)kc * (CHK / 32) * 6144;

    STAGE(0, 0)
    __syncthreads();

    for (int st = 0; st < NSTEP; ++st) {
        const int b = st & 1;
        if (st + 1 < NSTEP) { STAGE(b ^ 1, st + 1) }

        const u16* base0 = &ldsb[b][l * 8];
        f32x16 acc0 = {0.f, 0.f, 0.f, 0.f, 0.f, 0.f, 0.f, 0.f,
                       0.f, 0.f, 0.f, 0.f, 0.f, 0.f, 0.f, 0.f};
        f32x16 acc1 = acc0;
#pragma unroll
        for (int ks = 0; ks < 2; ++ks) {
            short8 ch0 = *(const short8*)(base0 + 0 * 2048 + ks * 512);
            short8 cm0 = *(const short8*)(base0 + 1 * 2048 + ks * 512);
            short8 cl0 = *(const short8*)(base0 + 2 * 2048 + ks * 512);
            short8 ch1 = *(const short8*)(base0 + 0 * 2048 + (ks + 2) * 512);
            short8 cm1 = *(const short8*)(base0 + 1 * 2048 + (ks + 2) * 512);
            short8 cl1 = *(const short8*)(base0 + 2 * 2048 + (ks + 2) * 512);
            acc0 = __builtin_amdgcn_mfma_f32_32x32x16_bf16(ch0, Z[0][ks], acc0, 0, 0, 0);
            acc1 = __builtin_amdgcn_mfma_f32_32x32x16_bf16(ch1, Z[0][ks + 2], acc1, 0, 0, 0);
            acc0 = __builtin_amdgcn_mfma_f32_32x32x16_bf16(ch0, Z[1][ks], acc0, 0, 0, 0);
            acc1 = __builtin_amdgcn_mfma_f32_32x32x16_bf16(ch1, Z[1][ks + 2], acc1, 0, 0, 0);
            acc0 = __builtin_amdgcn_mfma_f32_32x32x16_bf16(cm0, Z[0][ks], acc0, 0, 0, 0);
            acc1 = __builtin_amdgcn_mfma_f32_32x32x16_bf16(cm1, Z[0][ks + 2], acc1, 0, 0, 0);
            acc0 = __builtin_amdgcn_mfma_f32_32x32x16_bf16(cm0, Z[1][ks], acc0, 0, 0, 0);
            acc1 = __builtin_amdgcn_mfma_f32_32x32x16_bf16(cm1, Z[1][ks + 2], acc1, 0, 0, 0);
            acc0 = __builtin_amdgcn_mfma_f32_32x32x16_bf16(cl0, Z[0][ks], acc0, 0, 0, 0);
            acc1 = __builtin_amdgcn_mfma_f32_32x32x16_bf16(cl1, Z[0][ks + 2], acc1, 0, 0, 0);
            acc0 = __builtin_amdgcn_mfma_f32_32x32x16_bf16(ch0, Z[2][ks], acc0, 0, 0, 0);
            acc1 = __builtin_amdgcn_mfma_f32_32x32x16_bf16(ch1, Z[2][ks + 2], acc1, 0, 0, 0);
        }

        // c2-adjust + in-lane best update (rows visited in increasing code order)
        const float* c2s = pc2 + st * 32 + hi * 4;
#pragma unroll
        for (int r = 0; r < 16; ++r) {
            const int rc = (r & 3) + 8 * (r >> 2);   // code row (without hi*4)
            const float val = fmaf(-0.5f, c2s[rc], acc0[r] + acc1[r]);
            const int ci = st * 32 + rc + hi * 4;
            if (val > bestv) { bestv = val; besti = ci; }
        }
        __syncthreads();   // stage(st+1) long since landed; guards buffer reuse
    }

    // merge the two code-halves of this vector (lane l <-> l^32)
    {
        const float ov = __shfl_xor(bestv, 32, 64);
        const int   oi = __shfl_xor(besti, 32, 64);
        if (ov > bestv || (ov == bestv && oi < besti)) { bestv = ov; besti = oi; }
    }
    if (l < 32) {
        const u64 pack = ((u64)fmono(-bestv) << 32) | (u32)(code_base + besti);
        atomicMin(&minp[m0 + l], pack);
    }
}

// ---------------- quantized_st / indices / counts / vq partial (channel-split 4x) ----------------
__global__ __launch_bounds__(256) void gather_kernel(const float* __restrict__ z,
                                                     const float* __restrict__ cb,
                                                     const u64* __restrict__ minp,
                                                     float* __restrict__ out,
                                                     float* __restrict__ counts,
                                                     float* __restrict__ scal) {
    const int n = blockIdx.x * 256 + threadIdx.x;
    const int cg = blockIdx.y;               // 0..3: 16-channel slice
    const int bi = (int)(u32)(minp[n] & 0xFFFFFFFFu);
    if (cg == 0) {
        out[OFF_IDX + n] = (float)bi;
        atomicAdd(&counts[bi], 1.0f);
    }

    const int b = n >> 10, h = n & 1023;
    const size_t off = (size_t)b * BPLANE + (size_t)cg * 16 * HW + h;
    const float* zp = z + off;
    const float* cp = cb + (size_t)bi * DIMV + cg * 16;
    float* qp = out + OFF_Q + off;
    float acc = 0.f;
#pragma unroll
    for (int c = 0; c < 16; ++c) {
        float zv = zp[c * HW];
        float q = cp[c];
        float df = q - zv;
        acc = fmaf(df, df, acc);
        qp[c * HW] = zv + df;
    }
    for (int off2 = 32; off2 > 0; off2 >>= 1) acc += __shfl_down(acc, off2, 64);
    __shared__ float red[4];
    if ((threadIdx.x & 63) == 0) red[threadIdx.x >> 6] = acc;
    __syncthreads();
    if (threadIdx.x == 0) atomicAdd(&scal[0], (red[0] + red[1]) + (red[2] + red[3]));
}

// ---------------- prefix scan of counts -> offs + fused stats + scalar outputs ----------------
__global__ __launch_bounds__(256) void prefix_kernel(const float* __restrict__ counts,
                                                     const float* __restrict__ cs,
                                                     float* __restrict__ out,
                                                     int* __restrict__ offs,
                                                     float* __restrict__ scal) {
    __shared__ int part[256];
    __shared__ float r0[4], r1[4], r2[4];
    const int t = threadIdx.x;
    const int base = t * 32;
    int loc[32];
    int s = 0;
    float sncs = 0.f, spl = 0.f, sact = 0.f;
#pragma unroll
    for (int j = 0; j < 32; ++j) {
        const int c = (int)counts[base + j];
        loc[j] = s; s += c;
        const float cnt = (float)c;
        const float ncs = 0.99f * cs[base + j] + 0.01f * cnt;
        out[OFF_NCS + base + j] = ncs;
        const float p = cnt * (1.0f / 32768.0f);
        spl += p * logf(p + 1e-10f);
        sact += (cnt > 0) ? 1.f : 0.f;
        sncs += ncs;
    }
    part[t] = s;
    __syncthreads();
    for (int off = 1; off < 256; off <<= 1) {
        int v = (t >= off) ? part[t - off] : 0;
        __syncthreads();
        part[t] += v;
        __syncthreads();
    }
    const int excl = part[t] - s;
#pragma unroll
    for (int j = 0; j < 32; ++j) offs[base + j] = excl + loc[j];

    for (int off = 32; off > 0; off >>= 1) {
        sncs += __shfl_down(sncs, off, 64);
        spl  += __shfl_down(spl,  off, 64);
        sact += __shfl_down(sact, off, 64);
    }
    const int w = t >> 6;
    if ((t & 63) == 0) { r0[w] = sncs; r1[w] = spl; r2[w] = sact; }
    __syncthreads();
    if (t == 0) {
        const float nt = (r0[0] + r0[1]) + (r0[2] + r0[3]);
        scal[1] = nt;
        out[OFF_LOSS] = scal[0] * (1.0f / 2097152.0f);
        out[OFF_PPL]  = expf(-((r1[0] + r1[1]) + (r1[2] + r1[3])));
        out[OFF_ACT]  = (r2[0] + r2[1]) + (r2[2] + r2[3]);
    }
}

// ---------------- scatter vector ids into buckets ----------------
__global__ __launch_bounds__(256) void scatter_kernel(const float* __restrict__ outIdx,
                                                      int* __restrict__ offs,
                                                      int* __restrict__ perm) {
    const int n = blockIdx.x * 256 + threadIdx.x;
    const int bi = (int)outIdx[n];
    const int pos = atomicAdd(&offs[bi], 1);
    perm[pos] = n;
}

// ---------------- per-code segmented sum + fused new_embed_avg / new_codebook ----------------
__global__ __launch_bounds__(256) void segsum_kernel(const float* __restrict__ z,
                                                     const float* __restrict__ counts,
                                                     const int* __restrict__ offs,
                                                     const int* __restrict__ perm,
                                                     const float* __restrict__ ea,
                                                     float* __restrict__ out,
                                                     const float* __restrict__ scal) {
    const int w = threadIdx.x >> 6;
    const int c = threadIdx.x & 63;
    const int k = blockIdx.x * 4 + w;
    const int end = offs[k];               // post-scatter: bucket end
    const int cnt = (int)counts[k];
    float s = 0.f;
    for (int m = end - cnt; m < end; ++m) {
        const int n = perm[m];
        s += z[(size_t)(n >> 10) * BPLANE + (size_t)c * HW + (n & 1023)];
    }
    const int idx = k * DIMV + c;
    const float nea = 0.99f * ea[idx] + 0.01f * s;
    out[OFF_NEA + idx] = nea;
    const float nt = scal[1];
    const float ncs = out[OFF_NCS + k];
    const float sm = ((ncs + 1e-5f) / (nt + 0.08192f)) * nt;
    out[OFF_NCB + idx] = nea / sm;
}

extern "C" void kernel_launch(void* const* d_in, const int* in_sizes, int n_in,
                              void* d_out, int out_size, void* d_ws, size_t ws_size,
                              hipStream_t stream) {
    const float* z  = (const float*)d_in[0];
    const float* cb = (const float*)d_in[1];
    const float* cs = (const float*)d_in[2];
    const float* ea = (const float*)d_in[3];
    float* out = (float*)d_out;
    float* ws  = (float*)d_ws;

    float* counts = ws + WS_COUNTS;
    float* scal   = ws + WS_SCAL;
    float* c2     = ws + WS_C2;
    u64*   minp   = (u64*)(ws + WS_MINP);
    int*   offs   = (int*)(ws + WS_OFFS);
    int*   perm   = (int*)(ws + WS_PERM);
    u16*   cbf    = (u16*)(ws + WS_CBF);

    cbsplit_kernel<<<KC / 4, 256, 0, stream>>>(cb, cbf, c2, counts, scal, minp);
    nn_kernel<<<dim3(256, NKCH), 256, 0, stream>>>(z, cbf, c2, minp);
    gather_kernel<<<dim3(NVEC / 256, 4), 256, 0, stream>>>(z, cb, minp, out, counts, scal);
    prefix_kernel<<<1, 256, 0, stream>>>(counts, cs, out, offs, scal);
    scatter_kernel<<<NVEC / 256, 256, 0, stream>>>(out + OFF_IDX, offs, perm);
    segsum_kernel<<<KC / 4, 256, 0, stream>>>(z, counts, offs, perm, ea, out, scal);
}

// Round 19
// 249.967 us; speedup vs baseline: 1.1309x; 1.1309x over previous
//
#include <hip/hip_runtime.h>
#include <math.h>

typedef unsigned short u16;
typedef unsigned int u32;
typedef unsigned long long u64;
typedef __attribute__((ext_vector_type(8))) short short8;
typedef __attribute__((ext_vector_type(4))) float f32x4;

#define NVEC   32768
#define DIMV   64
#define KC     8192
#define NKCH   8
#define CHK    1024
#define HW     1024
#define BPLANE 65536
#define NSTEP  (CHK / 32)   // 32 staged steps of 32 codes

// output offsets (floats)
#define OFF_Q    0
#define OFF_IDX  2097152
#define OFF_LOSS 2129920
#define OFF_PPL  2129921
#define OFF_ACT  2129922
#define OFF_NCB  2129923
#define OFF_NCS  2654211
#define OFF_NEA  2662403

// workspace offsets (floats)
#define WS_COUNTS 0        // 8192
#define WS_SCAL   8192     // 8
#define WS_C2     8200     // 8192
#define WS_MINP   16400    // 65536 (32768 u64, 8B-aligned)
#define WS_OFFS   81936    // 8192 int
#define WS_PERM   90128    // 32768 int
#define WS_CBF    122896   // 786432 floats = 1572864 u16 (fragment-major 3-split)

__device__ __forceinline__ u16 f2bf(float x) {
    u32 u = __float_as_uint(x);
    u += 0x7fffu + ((u >> 16) & 1u);   // RNE
    return (u16)(u >> 16);
}
__device__ __forceinline__ float bf2f(u16 h) {
    return __uint_as_float(((u32)h) << 16);
}
__device__ __forceinline__ u32 fmono(float f) {   // monotone float->u32
    u32 b = __float_as_uint(f);
    return (b & 0x80000000u) ? ~b : (b | 0x80000000u);
}

// ---------------- codebook bf16 3-split (fragment-major) + c2 + ws init ----------------
// cbf layout per 16-code tile ti (3072 u16): parts p=0..5 {h0,h1,m0,m1,l0,l1} x 1KB,
// within a part lane l = (code&15) + ((d>>3)&3)*16 holds 8 u16 at l*8 (+ e = d&7).
// 6-term is REQUIRED: 3-term (r11) flipped indices (absmax 1952) — margin floor < 4e-4.
__global__ __launch_bounds__(256) void cbsplit_kernel(const float* __restrict__ cb,
                                                      u16* __restrict__ cbf,
                                                      float* __restrict__ c2,
                                                      float* __restrict__ counts,
                                                      float* __restrict__ scal,
                                                      u64* __restrict__ minp) {
    const int t = threadIdx.x;
    const int gid = blockIdx.x * 256 + t;
    if (gid < 8192) counts[gid] = 0.f;
    if (gid < 8) scal[gid] = 0.f;
    if (gid < NVEC) minp[gid] = ~0ull;

    const int k = blockIdx.x * 4 + (t >> 6);
    const int d = t & 63;
    const int idx = k * DIMV + d;
    float x = cb[idx];
    u16 hb = f2bf(x);  float fh = bf2f(hb);
    float r1 = x - fh; u16 mb = f2bf(r1); float fm = bf2f(mb);
    float r2 = r1 - fm; u16 lb = f2bf(r2);
    const int ti = k >> 4, row = k & 15;
    const int half = d >> 5;
    const int cg = (d >> 3) & 3;
    const int le = row + cg * 16;
    u16* base = cbf + (size_t)ti * 3072 + le * 8 + (d & 7);
    base[(0 + half) * 512] = hb;
    base[(2 + half) * 512] = mb;
    base[(4 + half) * 512] = lb;
    float s = x * x;
    for (int off = 32; off > 0; off >>= 1) s += __shfl_down(s, off, 64);
    if (d == 0) c2[k] = s;
}

// ---------------- MFMA nearest-neighbor search (proven optimum config) ----------------
// 16x16x32, Mw=32, KSTEP=32, LDS 24576, (256,4): every perturbation tested worse or
// null — KSTEP=64 (r15 -10%), 32x32 shape (r17/r18 -15%), sc2-LDS (r12 null), waves
// 2/3 (null), Mw=64 (spills any cap<150), 3-term (r11 wrong). Residual ~36% =
// step-boundary lockstep (structural).
#define NN_COMPUTE(Bh0, Bh1, Bm0, Bm1, Bl0, Bl1, CM, NTI)                          \
    _Pragma("unroll")                                                               \
    for (int i = 0; i < 2; ++i) {                                                   \
        f32x4 acc = {CM, CM, CM, CM};                                               \
        acc = __builtin_amdgcn_mfma_f32_16x16x32_bf16(A[i][0][0], Bh0, acc, 0, 0, 0);\
        acc = __builtin_amdgcn_mfma_f32_16x16x32_bf16(A[i][0][1], Bh1, acc, 0, 0, 0);\
        acc = __builtin_amdgcn_mfma_f32_16x16x32_bf16(A[i][1][0], Bh0, acc, 0, 0, 0);\
        acc = __builtin_amdgcn_mfma_f32_16x16x32_bf16(A[i][1][1], Bh1, acc, 0, 0, 0);\
        acc = __builtin_amdgcn_mfma_f32_16x16x32_bf16(A[i][0][0], Bm0, acc, 0, 0, 0);\
        acc = __builtin_amdgcn_mfma_f32_16x16x32_bf16(A[i][0][1], Bm1, acc, 0, 0, 0);\
        acc = __builtin_amdgcn_mfma_f32_16x16x32_bf16(A[i][1][0], Bm0, acc, 0, 0, 0);\
        acc = __builtin_amdgcn_mfma_f32_16x16x32_bf16(A[i][1][1], Bm1, acc, 0, 0, 0);\
        acc = __builtin_amdgcn_mfma_f32_16x16x32_bf16(A[i][2][0], Bh0, acc, 0, 0, 0);\
        acc = __builtin_amdgcn_mfma_f32_16x16x32_bf16(A[i][2][1], Bh1, acc, 0, 0, 0);\
        acc = __builtin_amdgcn_mfma_f32_16x16x32_bf16(A[i][0][0], Bl0, acc, 0, 0, 0);\
        acc = __builtin_amdgcn_mfma_f32_16x16x32_bf16(A[i][0][1], Bl1, acc, 0, 0, 0);\
        _Pragma("unroll")                                                           \
        for (int r = 0; r < 4; ++r) {                                               \
            float a = acc[r];                                                       \
            if (a > bestv[i][r]) { bestv[i][r] = a; bestn[i][r] = (NTI); }          \
        }                                                                           \
    }

#define STAGE(B, ST)                                                                \
    _Pragma("unroll")                                                               \
    for (int j = 0; j < 3; ++j) {                                                   \
        const u16* gs = pcbf + (size_t)(ST) * 6144 + j * 2048 + tl * 8;             \
        u16* ld = &ldsb[B][j * 2048 + wv * 512];                                    \
        __builtin_amdgcn_global_load_lds(                                           \
            (const __attribute__((address_space(1))) void*)gs,                      \
            (__attribute__((address_space(3))) void*)ld, 16, 0, 0);                 \
    }

__global__ __launch_bounds__(256, 4) void nn_kernel(const float* __restrict__ z,
                                                    const u16* __restrict__ cbf,
                                                    const float* __restrict__ c2,
                                                    u64* __restrict__ minp) {
    __shared__ __align__(16) u16 ldsb[2][6144];   // 24KB: 2 buf x 32 codes x 6 parts
    const int tl = threadIdx.x;
    const int l  = tl & 63;
    const int wv = tl >> 6;
    const int vg = blockIdx.x;      // 0..255 vector groups (128 vecs)
    const int kc = blockIdx.y;      // 0..7 code chunks (1024 codes)
    const int m0 = vg * 128 + wv * 32;
    const int lr = l & 15;
    const int lg = l >> 4;

    short8 A[2][3][2];
#pragma unroll
    for (int i = 0; i < 2; ++i) {
        const int vec = m0 + i * 16 + lr;
        const float* zp = z + (size_t)(vec >> 10) * BPLANE + (vec & 1023);
#pragma unroll
        for (int s = 0; s < 2; ++s) {
            short8 ah, am, al;
#pragma unroll
            for (int e = 0; e < 8; ++e) {
                const int k = s * 32 + lg * 8 + e;
                float x = zp[k * HW];
                u16 hb = f2bf(x);   float fh = bf2f(hb);
                float r1 = x - fh;  u16 mb = f2bf(r1); float fm = bf2f(mb);
                float r2 = r1 - fm; u16 lb = f2bf(r2);
                ah[e] = (short)hb; am[e] = (short)mb; al[e] = (short)lb;
            }
            A[i][0][s] = ah; A[i][1][s] = am; A[i][2][s] = al;
        }
    }

    float bestv[2][4];
    int   bestn[2][4];
#pragma unroll
    for (int i = 0; i < 2; ++i)
#pragma unroll
        for (int r = 0; r < 4; ++r) { bestv[i][r] = -3.4e38f; bestn[i][r] = 0; }

    const int code_base = kc * CHK;
    const float* pc2 = c2 + code_base + lr;
    const u16* pcbf = cbf + (size_t)kc * (CHK / 16) * 3072;

    STAGE(0, 0)
    __syncthreads();

    for (int st = 0; st < NSTEP; ++st) {
        const int b = st & 1;
        const float cmA = -0.5f * pc2[(st * 2) * 16];
        const float cmB = -0.5f * pc2[(st * 2 + 1) * 16];
        if (st + 1 < NSTEP) { STAGE(b ^ 1, st + 1) }

        const u16* baseA = &ldsb[b][l * 8];
        {
            short8 h0 = *(const short8*)(baseA);
            short8 h1 = *(const short8*)(baseA + 512);
            short8 m0f = *(const short8*)(baseA + 1024);
            short8 m1f = *(const short8*)(baseA + 1536);
            short8 l0f = *(const short8*)(baseA + 2048);
            short8 l1f = *(const short8*)(baseA + 2560);
            NN_COMPUTE(h0, h1, m0f, m1f, l0f, l1f, cmA, st * 2)
        }
        {
            const u16* baseB = baseA + 3072;
            short8 h0 = *(const short8*)(baseB);
            short8 h1 = *(const short8*)(baseB + 512);
            short8 m0f = *(const short8*)(baseB + 1024);
            short8 m1f = *(const short8*)(baseB + 1536);
            short8 l0f = *(const short8*)(baseB + 2048);
            short8 l1f = *(const short8*)(baseB + 2560);
            NN_COMPUTE(h0, h1, m0f, m1f, l0f, l1f, cmB, st * 2 + 1)
        }
        __syncthreads();
    }

#pragma unroll
    for (int i = 0; i < 2; ++i)
#pragma unroll
        for (int r = 0; r < 4; ++r) {
            float v = bestv[i][r];
            int idx = bestn[i][r] * 16 + lr;
#pragma unroll
            for (int mk = 1; mk < 16; mk <<= 1) {
                float ov = __shfl_xor(v, mk, 64);
                int   oi = __shfl_xor(idx, mk, 64);
                if (ov > v || (ov == v && oi < idx)) { v = ov; idx = oi; }
            }
            if (lr == 0) {
                const int vec = m0 + i * 16 + lg * 4 + r;
                const u64 pack = ((u64)fmono(-v) << 32) | (u32)(code_base + idx);
                atomicMin(&minp[vec], pack);
            }
        }
}

// ---------------- write quantized_st / indices, count atomics, vq partial ----------------
__global__ __launch_bounds__(256) void gather_kernel(const float* __restrict__ z,
                                                     const float* __restrict__ cb,
                                                     const u64* __restrict__ minp,
                                                     float* __restrict__ out,
                                                     float* __restrict__ counts,
                                                     float* __restrict__ scal) {
    const int n = blockIdx.x * 256 + threadIdx.x;
    const int bi = (int)(u32)(minp[n] & 0xFFFFFFFFu);
    out[OFF_IDX + n] = (float)bi;
    atomicAdd(&counts[bi], 1.0f);

    const int b = n >> 10, h = n & 1023;
    const float* zp = z + (size_t)b * BPLANE + h;
    const float* cp = cb + (size_t)bi * DIMV;
    float* qp = out + OFF_Q + (size_t)b * BPLANE + h;
    float acc = 0.f;
#pragma unroll
    for (int c = 0; c < DIMV; ++c) {
        float zv = zp[c * HW];
        float q = cp[c];
        float df = q - zv;
        acc = fmaf(df, df, acc);
        qp[c * HW] = zv + df;
    }
    for (int off = 32; off > 0; off >>= 1) acc += __shfl_down(acc, off, 64);
    __shared__ float red[4];
    if ((threadIdx.x & 63) == 0) red[threadIdx.x >> 6] = acc;
    __syncthreads();
    if (threadIdx.x == 0) atomicAdd(&scal[0], (red[0] + red[1]) + (red[2] + red[3]));
}

// ---------------- prefix scan of counts -> offs + fused stats + scalar outputs ----------------
__global__ __launch_bounds__(256) void prefix_kernel(const float* __restrict__ counts,
                                                     const float* __restrict__ cs,
                                                     float* __restrict__ out,
                                                     int* __restrict__ offs,
                                                     float* __restrict__ scal) {
    __shared__ int part[256];
    __shared__ float r0[4], r1[4], r2[4];
    const int t = threadIdx.x;
    const int base = t * 32;
    int loc[32];
    int s = 0;
    float sncs = 0.f, spl = 0.f, sact = 0.f;
#pragma unroll
    for (int j = 0; j < 32; ++j) {
        const int c = (int)counts[base + j];
        loc[j] = s; s += c;
        const float cnt = (float)c;
        const float ncs = 0.99f * cs[base + j] + 0.01f * cnt;
        out[OFF_NCS + base + j] = ncs;
        const float p = cnt * (1.0f / 32768.0f);
        spl += p * logf(p + 1e-10f);
        sact += (cnt > 0) ? 1.f : 0.f;
        sncs += ncs;
    }
    part[t] = s;
    __syncthreads();
    for (int off = 1; off < 256; off <<= 1) {
        int v = (t >= off) ? part[t - off] : 0;
        __syncthreads();
        part[t] += v;
        __syncthreads();
    }
    const int excl = part[t] - s;
#pragma unroll
    for (int j = 0; j < 32; ++j) offs[base + j] = excl + loc[j];

    for (int off = 32; off > 0; off >>= 1) {
        sncs += __shfl_down(sncs, off, 64);
        spl  += __shfl_down(spl,  off, 64);
        sact += __shfl_down(sact, off, 64);
    }
    const int w = t >> 6;
    if ((t & 63) == 0) { r0[w] = sncs; r1[w] = spl; r2[w] = sact; }
    __syncthreads();
    if (t == 0) {
        const float nt = (r0[0] + r0[1]) + (r0[2] + r0[3]);
        scal[1] = nt;
        out[OFF_LOSS] = scal[0] * (1.0f / 2097152.0f);
        out[OFF_PPL]  = expf(-((r1[0] + r1[1]) + (r1[2] + r1[3])));
        out[OFF_ACT]  = (r2[0] + r2[1]) + (r2[2] + r2[3]);
    }
}

// ---------------- scatter vector ids into buckets ----------------
__global__ __launch_bounds__(256) void scatter_kernel(const float* __restrict__ outIdx,
                                                      int* __restrict__ offs,
                                                      int* __restrict__ perm) {
    const int n = blockIdx.x * 256 + threadIdx.x;
    const int bi = (int)outIdx[n];
    const int pos = atomicAdd(&offs[bi], 1);
    perm[pos] = n;
}

// ---------------- per-code segmented sum + fused new_embed_avg / new_codebook ----------------
__global__ __launch_bounds__(256) void segsum_kernel(const float* __restrict__ z,
                                                     const float* __restrict__ counts,
                                                     const int* __restrict__ offs,
                                                     const int* __restrict__ perm,
                                                     const float* __restrict__ ea,
                                                     float* __restrict__ out,
                                                     const float* __restrict__ scal) {
    const int w = threadIdx.x >> 6;
    const int c = threadIdx.x & 63;
    const int k = blockIdx.x * 4 + w;
    const int end = offs[k];               // post-scatter: bucket end
    const int cnt = (int)counts[k];
    float s = 0.f;
    for (int m = end - cnt; m < end; ++m) {
        const int n = perm[m];
        s += z[(size_t)(n >> 10) * BPLANE + (size_t)c * HW + (n & 1023)];
    }
    const int idx = k * DIMV + c;
    const float nea = 0.99f * ea[idx] + 0.01f * s;
    out[OFF_NEA + idx] = nea;
    const float nt = scal[1];
    const float ncs = out[OFF_NCS + k];
    const float sm = ((ncs + 1e-5f) / (nt + 0.08192f)) * nt;
    out[OFF_NCB + idx] = nea / sm;
}

extern "C" void kernel_launch(void* const* d_in, const int* in_sizes, int n_in,
                              void* d_out, int out_size, void* d_ws, size_t ws_size,
                              hipStream_t stream) {
    const float* z  = (const float*)d_in[0];
    const float* cb = (const float*)d_in[1];
    const float* cs = (const float*)d_in[2];
    const float* ea = (const float*)d_in[3];
    float* out = (float*)d_out;
    float* ws  = (float*)d_ws;

    float* counts = ws + WS_COUNTS;
    float* scal   = ws + WS_SCAL;
    float* c2     = ws + WS_C2;
    u64*   minp   = (u64*)(ws + WS_MINP);
    int*   offs   = (int*)(ws + WS_OFFS);
    int*   perm   = (int*)(ws + WS_PERM);
    u16*   cbf    = (u16*)(ws + WS_CBF);

    cbsplit_kernel<<<KC / 4, 256, 0, stream>>>(cb, cbf, c2, counts, scal, minp);
    nn_kernel<<<dim3(256, NKCH), 256, 0, stream>>>(z, cbf, c2, minp);
    gather_kernel<<<NVEC / 256, 256, 0, stream>>>(z, cb, minp, out, counts, scal);
    prefix_kernel<<<1, 256, 0, stream>>>(counts, cs, out, offs, scal);
    scatter_kernel<<<NVEC / 256, 256, 0, stream>>>(out + OFF_IDX, offs, perm);
    segsum_kernel<<<KC / 4, 256, 0, stream>>>(z, counts, offs, perm, ea, out, scal);
}